// Round 5
// baseline (1005.480 us; speedup 1.0000x reference)
//
#include <hip/hip_runtime.h>
#include <hip/hip_bf16.h>

#define NN 50000
#define EE 800000
#define DH 128
#define RDIM 32
#define RR 16
#define HRD 160
#define NB 16
#define SCAN_B ((NN + 255) / 256)

typedef float4 f4;

// ---------------- CSR build ----------------

__global__ __launch_bounds__(256) void k_count(const int* __restrict__ dst,
                                               const int* __restrict__ rel,
                                               int* deg, int* cnt) {
    int e = blockIdx.x * 256 + threadIdx.x;
    if (e < EE) {
        int d = dst[e];
        atomicAdd(&deg[d], 1);
        atomicAdd(&cnt[d * RR + rel[e]], 1);
    }
}

__global__ __launch_bounds__(256) void k_scan_part(const int* __restrict__ deg,
                                                   int* rp, int* bsum) {
    __shared__ int s[256];
    int tid = threadIdx.x;
    int i = blockIdx.x * 256 + tid;
    int v = (i < NN) ? deg[i] : 0;
    s[tid] = v;
    __syncthreads();
    for (int off = 1; off < 256; off <<= 1) {
        int t = (tid >= off) ? s[tid - off] : 0;
        __syncthreads();
        s[tid] += t;
        __syncthreads();
    }
    if (i < NN) rp[i] = s[tid] - v;         // exclusive within block
    if (tid == 255) bsum[blockIdx.x] = s[255];
}

__global__ __launch_bounds__(256) void k_scan_bsum(const int* __restrict__ bsum, int* boff) {
    __shared__ int s[256];
    int tid = threadIdx.x;
    int v = (tid < SCAN_B) ? bsum[tid] : 0;
    s[tid] = v;
    __syncthreads();
    for (int off = 1; off < 256; off <<= 1) {
        int t = (tid >= off) ? s[tid - off] : 0;
        __syncthreads();
        s[tid] += t;
        __syncthreads();
    }
    boff[tid] = s[tid] - v;                  // exclusive block offsets
}

__global__ __launch_bounds__(256) void k_scan_add(const int* __restrict__ boff,
                                                  int* rp, int* fill) {
    int i = blockIdx.x * 256 + threadIdx.x;
    if (i < NN) {
        int v = rp[i] + boff[blockIdx.x];
        rp[i] = v;
        fill[i] = v;
    }
    if (i == 0) rp[NN] = EE;
}

__global__ __launch_bounds__(256) void k_fill(const int* __restrict__ src,
                                              const int* __restrict__ dst,
                                              int* fill, int* col) {
    int e = blockIdx.x * 256 + threadIdx.x;
    if (e < EE) {
        int p = atomicAdd(&fill[dst[e]], 1);
        col[p] = src[e];
    }
}

// ---------------- weight precompute ----------------
// Wcat[l][f][0..127]   = self_W[l][f][k]
// Wcat[l][f][128..255] = (neigh_W[l] @ msg_Wh[l])[f][k]
__global__ __launch_bounds__(256) void k_prep_wcat(const float* __restrict__ selfW,
                                                   const float* __restrict__ neighW,
                                                   const float* __restrict__ msgW,
                                                   float* __restrict__ Wcat) {
    int l = blockIdx.y;
    int t = threadIdx.x;
    int f = blockIdx.x * 16 + (t >> 4);
    int kc = (t & 15) * 8;
    const float* sW = selfW + (size_t)l * DH * DH + f * DH;
    const float* nW = neighW + (size_t)l * DH * DH + f * DH;
    const float* mW = msgW + (size_t)l * DH * HRD;
    float* out = Wcat + (size_t)l * DH * 256 + f * 256;
    #pragma unroll
    for (int i = 0; i < 8; ++i) out[kc + i] = sW[kc + i];
    for (int i = 0; i < 8; ++i) {
        int k = kc + i;
        float acc = 0.f;
        for (int j = 0; j < DH; ++j) acc += nW[j] * mW[j * HRD + k];
        out[128 + k] = acc;
    }
}

// Mmat[l] is [18][128]:
//  rows 0..15: rel_emb[l] @ (neigh_W[l] @ msg_Wr[l]).T
//  row  16   : neigh_W[l] @ msg_b[l]     (gated by deg>0)
//  row  17   : self_b[l] + neigh_b[l]    (always on)
__global__ __launch_bounds__(128) void k_prep_m(const float* __restrict__ relE,
                                                const float* __restrict__ msgW,
                                                const float* __restrict__ msgB,
                                                const float* __restrict__ neighW,
                                                const float* __restrict__ selfB,
                                                const float* __restrict__ neighB,
                                                float* __restrict__ Mmat) {
    int l = blockIdx.x;
    int f = threadIdx.x;
    __shared__ float wcr[DH * 33];
    const float* nW = neighW + (size_t)l * DH * DH + f * DH;
    const float* mW = msgW + (size_t)l * DH * HRD;
    for (int c = 0; c < RDIM; ++c) {
        float acc = 0.f;
        for (int j = 0; j < DH; ++j) acc += nW[j] * mW[j * HRD + 128 + c];
        wcr[f * 33 + c] = acc;
    }
    __syncthreads();
    float* M = Mmat + (size_t)l * 18 * DH;
    for (int r = 0; r < RR; ++r) {
        const float* re = relE + (size_t)l * RR * RDIM + r * RDIM;
        float acc = 0.f;
        for (int c = 0; c < RDIM; ++c) acc += re[c] * wcr[f * 33 + c];
        M[r * DH + f] = acc;
    }
    {
        const float* mb = msgB + (size_t)l * DH;
        float acc = 0.f;
        for (int j = 0; j < DH; ++j) acc += nW[j] * mb[j];
        M[16 * DH + f] = acc;
    }
    M[17 * DH + f] = selfB[(size_t)l * DH + f] + neighB[(size_t)l * DH + f];
}

// ---------------- input projection: h = x @ in_W.T + in_b ----------------
__global__ __launch_bounds__(256) void k_inproj(const float* __restrict__ x,
                                                const float* __restrict__ inW,
                                                const float* __restrict__ inB,
                                                float* __restrict__ hout) {
    __shared__ f4 u[NB][32];
    int t = threadIdx.x;
    int n0 = blockIdx.x * NB;
    const f4* x4 = (const f4*)x;
    #pragma unroll
    for (int i = 0; i < 2; ++i) {
        int s = t + i * 256;            // 512 slots = 16 rows * 32 f4
        int n = s >> 5, q = s & 31;
        u[n][q] = x4[(size_t)(n0 + n) * 32 + q];
    }
    __syncthreads();
    int fi = t & 63, g = t >> 6;
    const f4* W4 = (const f4*)inW;
    float acc[4][2];
    #pragma unroll
    for (int nn = 0; nn < 4; ++nn) { acc[nn][0] = 0.f; acc[nn][1] = 0.f; }
    #pragma unroll 4
    for (int k4 = 0; k4 < 32; ++k4) {
        f4 w0 = W4[fi * 32 + k4];
        f4 w1 = W4[(fi + 64) * 32 + k4];
        #pragma unroll
        for (int nn = 0; nn < 4; ++nn) {
            f4 uv = u[g * 4 + nn][k4];
            acc[nn][0] += uv.x * w0.x + uv.y * w0.y + uv.z * w0.z + uv.w * w0.w;
            acc[nn][1] += uv.x * w1.x + uv.y * w1.y + uv.z * w1.z + uv.w * w1.w;
        }
    }
    float b0 = inB[fi], b1 = inB[fi + 64];
    #pragma unroll
    for (int nn = 0; nn < 4; ++nn) {
        int node = n0 + g * 4 + nn;
        hout[(size_t)node * DH + fi] = acc[nn][0] + b0;
        hout[(size_t)node * DH + fi + 64] = acc[nn][1] + b1;
    }
}

// ---------------- segment sum of h[src] into S (pre-divided by deg) ----------------
__global__ __launch_bounds__(256) void k_seg(const float* __restrict__ h,
                                             const int* __restrict__ rp,
                                             const int* __restrict__ col,
                                             float* __restrict__ S) {
    int wid = threadIdx.x >> 6, lane = threadIdx.x & 63;
    int n = blockIdx.x * 4 + wid;
    if (n >= NN) return;
    int beg = rp[n], end = rp[n + 1];
    const float2* h2 = (const float2*)h;
    float ax = 0.f, ay = 0.f;
    for (int j0 = beg; j0 < end; j0 += 64) {
        int myc = (j0 + lane < end) ? col[j0 + lane] : 0;
        int m = min(64, end - j0);
        for (int jj = 0; jj < m; ++jj) {
            int sidx = __shfl(myc, jj, 64);
            float2 v = h2[(size_t)sidx * 64 + lane];
            ax += v.x;
            ay += v.y;
        }
    }
    float inv = 1.f / (float)max(end - beg, 1);
    float2 o;
    o.x = ax * inv;
    o.y = ay * inv;
    ((float2*)S)[(size_t)n * 64 + lane] = o;
}

// ---------------- fused layer ----------------
// out[n][f] = relu( [h[n] | S[n]] . Wcat[f][0..255]  +  sum_r crow[n][r]*Mmat[r][f] )
// Safe to run IN PLACE (hout == h): each block stages its own 16 node-rows of h
// into LDS before writing, and no block reads another block's rows.
// d_out is FLOAT32 (reference output dtype) — rounds 0-4 wrongly wrote bf16.
template <bool LAST>
__global__ __launch_bounds__(256) void k_layer(const float* __restrict__ h,
                                               const float* __restrict__ S,
                                               const int* __restrict__ cnt,
                                               const int* __restrict__ rp,
                                               const float* __restrict__ Wcat,
                                               const float* __restrict__ Mmat,
                                               float* __restrict__ hout) {
    __shared__ f4 u[NB][64];
    __shared__ float crow[NB][18];
    int t = threadIdx.x;
    int n0 = blockIdx.x * NB;
    const f4* h4 = (const f4*)h;
    const f4* S4 = (const f4*)S;
    #pragma unroll
    for (int i = 0; i < 4; ++i) {
        int s = t + i * 256;            // 1024 slots = 16 rows * 64 f4
        int n = s >> 6, q = s & 63;
        u[n][q] = (q < 32) ? h4[(size_t)(n0 + n) * 32 + q]
                           : S4[(size_t)(n0 + n) * 32 + (q - 32)];
    }
    // crow has NB*18 = 288 entries; block has 256 threads -> strided loop.
    for (int s = t; s < NB * 18; s += 256) {
        int n = s / 18, r = s - n * 18;
        int node = n0 + n;
        int d = rp[node + 1] - rp[node];
        float inv = 1.f / (float)max(d, 1);
        float v;
        if (r < 16) v = (float)cnt[node * RR + r] * inv;
        else if (r == 16) v = (d > 0) ? 1.f : 0.f;
        else v = 1.f;
        crow[n][r] = v;
    }
    __syncthreads();
    int fi = t & 63, g = t >> 6;
    const f4* W4 = (const f4*)Wcat;     // row f = 64 f4
    float acc[4][2];
    #pragma unroll
    for (int nn = 0; nn < 4; ++nn) { acc[nn][0] = 0.f; acc[nn][1] = 0.f; }
    #pragma unroll 4
    for (int k4 = 0; k4 < 64; ++k4) {
        f4 w0 = W4[fi * 64 + k4];
        f4 w1 = W4[(fi + 64) * 64 + k4];
        #pragma unroll
        for (int nn = 0; nn < 4; ++nn) {
            f4 uv = u[g * 4 + nn][k4];
            acc[nn][0] += uv.x * w0.x + uv.y * w0.y + uv.z * w0.z + uv.w * w0.w;
            acc[nn][1] += uv.x * w1.x + uv.y * w1.y + uv.z * w1.z + uv.w * w1.w;
        }
    }
    #pragma unroll
    for (int r = 0; r < 18; ++r) {
        float m0 = Mmat[r * DH + fi];
        float m1 = Mmat[r * DH + fi + 64];
        #pragma unroll
        for (int nn = 0; nn < 4; ++nn) {
            float c = crow[g * 4 + nn][r];
            acc[nn][0] += c * m0;
            acc[nn][1] += c * m1;
        }
    }
    #pragma unroll
    for (int nn = 0; nn < 4; ++nn) {
        int node = n0 + g * 4 + nn;
        float v0 = fmaxf(acc[nn][0], 0.f);
        float v1 = fmaxf(acc[nn][1], 0.f);
        hout[(size_t)node * DH + fi] = v0;
        hout[(size_t)node * DH + fi + 64] = v1;
        (void)sizeof(LAST);
    }
}

// ---------------- launch ----------------
extern "C" void kernel_launch(void* const* d_in, const int* in_sizes, int n_in,
                              void* d_out, int out_size, void* d_ws, size_t ws_size,
                              hipStream_t stream) {
    const float* x      = (const float*)d_in[0];
    const float* in_W   = (const float*)d_in[1];
    const float* in_b   = (const float*)d_in[2];
    const float* rel_e  = (const float*)d_in[3];
    const float* msg_W  = (const float*)d_in[4];
    const float* msg_b  = (const float*)d_in[5];
    const float* self_W = (const float*)d_in[6];
    const float* self_b = (const float*)d_in[7];
    const float* neigh_W= (const float*)d_in[8];
    const float* neigh_b= (const float*)d_in[9];
    const int* e_src    = (const int*)d_in[10];
    const int* e_dst    = (const int*)d_in[11];
    const int* r_ids    = (const int*)d_in[12];

    float* ws = (float*)d_ws;
    size_t off = 0;
    float* hA   = ws + off; off += (size_t)NN * DH;   // 25.6 MB
    float* S    = ws + off; off += (size_t)NN * DH;   // 25.6 MB
    float* Wcat = ws + off; off += 2 * DH * 256;
    float* Mmat = ws + off; off += 2 * 18 * DH;
    int* deg  = (int*)(ws + off);
    int* cnt  = deg + NN;
    int* rp   = cnt + (size_t)NN * RR;
    int* fill = rp + NN + 1;
    int* bsum = fill + NN;
    int* boff = bsum + 256;
    int* col  = boff + 256;
    // total ws: ~58.5 MB

    hipMemsetAsync(deg, 0, sizeof(int) * (NN + (size_t)NN * RR), stream);

    k_count<<<(EE + 255) / 256, 256, 0, stream>>>(e_dst, r_ids, deg, cnt);
    k_scan_part<<<SCAN_B, 256, 0, stream>>>(deg, rp, bsum);
    k_scan_bsum<<<1, 256, 0, stream>>>(bsum, boff);
    k_scan_add<<<SCAN_B, 256, 0, stream>>>(boff, rp, fill);
    k_fill<<<(EE + 255) / 256, 256, 0, stream>>>(e_src, e_dst, fill, col);

    k_prep_wcat<<<dim3(8, 2), 256, 0, stream>>>(self_W, neigh_W, msg_W, Wcat);
    k_prep_m<<<2, 128, 0, stream>>>(rel_e, msg_W, msg_b, neigh_W, self_b, neigh_b, Mmat);

    k_inproj<<<NN / NB, 256, 0, stream>>>(x, in_W, in_b, hA);

    k_seg<<<(NN + 3) / 4, 256, 0, stream>>>(hA, rp, col, S);
    k_layer<false><<<NN / NB, 256, 0, stream>>>(hA, S, cnt, rp, Wcat, Mmat, hA);  // in place

    k_seg<<<(NN + 3) / 4, 256, 0, stream>>>(hA, rp, col, S);
    k_layer<true><<<NN / NB, 256, 0, stream>>>(hA, S, cnt, rp, Wcat + DH * 256, Mmat + 18 * DH,
                                               (float*)d_out);
}

// Round 6
// 436.622 us; speedup vs baseline: 2.3029x; 2.3029x over previous
//
#include <hip/hip_runtime.h>
#include <hip/hip_bf16.h>

#define NN 50000
#define EE 800000
#define DH 128
#define RDIM 32
#define RR 16
#define HRD 160
#define HSW 272            // HS row width in ushort(bf16): [128 h | 128 S/agg | 16 cnt]
#define SCAN_B ((NN + 255) / 256)

typedef __attribute__((ext_vector_type(8))) short bf16x8;
typedef __attribute__((ext_vector_type(4))) float f32x4;

__device__ __forceinline__ ushort f2b(float v) {      // f32 -> bf16 RNE
    uint u = __float_as_uint(v);
    return (ushort)((u + 0x7fffu + ((u >> 16) & 1u)) >> 16);
}
__device__ __forceinline__ float b2f(ushort b) { return __uint_as_float(((uint)b) << 16); }

// ---------------- CSR build (proven) ----------------

__global__ __launch_bounds__(256) void k_count(const int* __restrict__ dst,
                                               const int* __restrict__ rel,
                                               int* deg, int* cnt) {
    int e = blockIdx.x * 256 + threadIdx.x;
    if (e < EE) {
        int d = dst[e];
        atomicAdd(&deg[d], 1);
        atomicAdd(&cnt[d * RR + rel[e]], 1);
    }
}

__global__ __launch_bounds__(256) void k_scan_part(const int* __restrict__ deg,
                                                   int* rp, int* bsum) {
    __shared__ int s[256];
    int tid = threadIdx.x;
    int i = blockIdx.x * 256 + tid;
    int v = (i < NN) ? deg[i] : 0;
    s[tid] = v;
    __syncthreads();
    for (int off = 1; off < 256; off <<= 1) {
        int t = (tid >= off) ? s[tid - off] : 0;
        __syncthreads();
        s[tid] += t;
        __syncthreads();
    }
    if (i < NN) rp[i] = s[tid] - v;
    if (tid == 255) bsum[blockIdx.x] = s[255];
}

__global__ __launch_bounds__(256) void k_scan_bsum(const int* __restrict__ bsum, int* boff) {
    __shared__ int s[256];
    int tid = threadIdx.x;
    int v = (tid < SCAN_B) ? bsum[tid] : 0;
    s[tid] = v;
    __syncthreads();
    for (int off = 1; off < 256; off <<= 1) {
        int t = (tid >= off) ? s[tid - off] : 0;
        __syncthreads();
        s[tid] += t;
        __syncthreads();
    }
    boff[tid] = s[tid] - v;
}

__global__ __launch_bounds__(256) void k_scan_add(const int* __restrict__ boff,
                                                  int* rp, int* fill) {
    int i = blockIdx.x * 256 + threadIdx.x;
    if (i < NN) {
        int v = rp[i] + boff[blockIdx.x];
        rp[i] = v;
        fill[i] = v;
    }
    if (i == 0) rp[NN] = EE;
}

__global__ __launch_bounds__(256) void k_fill(const int* __restrict__ src,
                                              const int* __restrict__ dst,
                                              int* fill, int* col) {
    int e = blockIdx.x * 256 + threadIdx.x;
    if (e < EE) {
        int p = atomicAdd(&fill[dst[e]], 1);
        col[p] = src[e];
    }
}

// ---------------- bf16 weight prep ----------------

__global__ __launch_bounds__(256) void k_prep_inWb(const float* __restrict__ w,
                                                   ushort* __restrict__ o) {
    int i = blockIdx.x * 256 + threadIdx.x;          // 16384
    o[i] = f2b(w[i]);
}

// B1[l][f][0..127] = msg_Wh[l][f][:];  B1[l][f][128+r] = (rel_emb[l] @ msg_Wr[l].T)[r][f]
__global__ __launch_bounds__(256) void k_prep_msgWb(const float* __restrict__ msgW,
                                                    const float* __restrict__ relE,
                                                    ushort* __restrict__ B1) {
    int t = threadIdx.x;                              // 1 block x 256
    int l = t >> 7, f = t & 127;
    const float* mw = msgW + (size_t)l * DH * HRD + f * HRD;
    ushort* out = B1 + (size_t)l * DH * 144 + f * 144;
    for (int k = 0; k < DH; ++k) out[k] = f2b(mw[k]);
    for (int r = 0; r < RR; ++r) {
        float acc = 0.f;
        for (int c = 0; c < RDIM; ++c)
            acc += relE[l * RR * RDIM + r * RDIM + c] * mw[DH + c];
        out[DH + r] = f2b(acc);
    }
}

// Wc2b[l][f][0..127]=self_W, [128..255]=neigh_W  (bf16)
__global__ __launch_bounds__(256) void k_prep_wc2b(const float* __restrict__ selfW,
                                                   const float* __restrict__ neighW,
                                                   ushort* __restrict__ o) {
    int idx = blockIdx.x * 256 + threadIdx.x;        // 65536
    int l = idx >> 15, rem = idx & 32767;
    int f = rem >> 8, k = rem & 255;
    float v = (k < DH) ? selfW[(size_t)l * DH * DH + f * DH + k]
                       : neighW[(size_t)l * DH * DH + f * DH + (k - DH)];
    o[idx] = f2b(v);
}

__global__ __launch_bounds__(256) void k_cntbf(const int* __restrict__ cnt,
                                               ushort* __restrict__ hs) {
    int idx = blockIdx.x * 256 + threadIdx.x;
    if (idx < NN * RR) {
        int n = idx >> 4, r = idx & 15;
        hs[(size_t)n * HSW + 256 + r] = f2b((float)cnt[idx]);
    }
}

// ---------------- gather: HS[n][128..255] = sum_{e:dst=n} HS[src_e][0..127] ----------
__global__ __launch_bounds__(256) void k_seg(ushort* __restrict__ hs,
                                             const int* __restrict__ rp,
                                             const int* __restrict__ col) {
    int wid = threadIdx.x >> 6, lane = threadIdx.x & 63;
    int n = blockIdx.x * 4 + wid;
    if (n >= NN) return;
    int beg = rp[n], end = rp[n + 1];
    float ax = 0.f, ay = 0.f;
    for (int j0 = beg; j0 < end; j0 += 64) {
        int myc = (j0 + lane < end) ? col[j0 + lane] : 0;
        int m = min(64, end - j0);
        for (int jj = 0; jj < m; ++jj) {
            int sidx = __shfl(myc, jj, 64);
            uint v = *(const uint*)(hs + (size_t)sidx * HSW + lane * 2);
            ax += b2f((ushort)(v & 0xffffu));
            ay += b2f((ushort)(v >> 16));
        }
    }
    uint packed = ((uint)f2b(ay) << 16) | (uint)f2b(ax);
    *(uint*)(hs + (size_t)n * HSW + 128 + lane * 2) = packed;
}

// ---------------- MFMA GEMM: out[n][f] = epi( sum_k A[n][k]*B[f][k] ) ----------------
// 256 thr = 4 waves (2M x 2N). Block tile 64 nodes x 128 f. K chunked at 128.
// AMODE 0: A = x (f32, convert)   1/2: A = HS bf16 (stride HSW), caller folds col offset.
// EPI 0: +b1 -> bf16 HS[:,0:128]          (inproj)
// EPI 1: v/max(deg,1) + (deg>0)*b1 -> bf16 HS[:,128:256]   (agg; cnt@RM folded via K=144)
// EPI 2: relu(v+b1+b2) -> bf16 HS[:,0:128]  EPI 3: same -> f32 d_out
template <int K, int EPI, int AMODE>
__global__ __launch_bounds__(256) void k_mm(const void* __restrict__ Araw,
                                            const ushort* __restrict__ B,
                                            const float* __restrict__ bias1,
                                            const float* __restrict__ bias2,
                                            const int* __restrict__ deg,
                                            ushort* __restrict__ hs,
                                            float* __restrict__ outf) {
    constexpr int KC = (K == 256) ? 128 : K;
    constexpr int NCH = K / KC;
    constexpr int KP = KC + 8;
    __shared__ ushort A_s[64][KP];
    __shared__ ushort B_s[128][KP];
    __shared__ int deg_s[64];
    int t = threadIdx.x;
    int n0 = blockIdx.x * 64;
    int lane = t & 63, wid = t >> 6;
    int wm = wid >> 1, wn = wid & 1;

    if (EPI == 1 && t < 64) {
        int node = n0 + t;
        deg_s[t] = (node < NN) ? deg[node] : 1;
    }

    f32x4 acc[2][4];
    #pragma unroll
    for (int mt = 0; mt < 2; ++mt)
        #pragma unroll
        for (int nt = 0; nt < 4; ++nt) acc[mt][nt] = (f32x4)0.0f;

    for (int ch = 0; ch < NCH; ++ch) {
        int kc0 = ch * KC;
        if (AMODE == 0) {
            const float4* x4 = (const float4*)Araw;            // [NN][128] f32
            for (int idx = t; idx < 64 * (KC / 4); idx += 256) {
                int r = idx / (KC / 4), c = idx % (KC / 4);
                int node = min(n0 + r, NN - 1);
                float4 v = x4[(size_t)node * 32 + c];
                ushort* dst = &A_s[r][c * 4];
                dst[0] = f2b(v.x); dst[1] = f2b(v.y);
                dst[2] = f2b(v.z); dst[3] = f2b(v.w);
            }
        } else {
            const ushort* Ab = (const ushort*)Araw;
            for (int idx = t; idx < 64 * (KC / 8); idx += 256) {
                int r = idx / (KC / 8), c = idx % (KC / 8);
                int node = min(n0 + r, NN - 1);
                *(uint4*)&A_s[r][c * 8] =
                    *(const uint4*)(Ab + (size_t)node * HSW + kc0 + c * 8);
            }
        }
        for (int idx = t; idx < 128 * (KC / 8); idx += 256) {
            int r = idx / (KC / 8), c = idx % (KC / 8);
            *(uint4*)&B_s[r][c * 8] =
                *(const uint4*)(B + (size_t)r * K + kc0 + c * 8);
        }
        __syncthreads();

        #pragma unroll
        for (int ks = 0; ks < KC / 32; ++ks) {
            int k0 = ks * 32 + (lane >> 4) * 8;
            bf16x8 af[2], bfr[4];
            #pragma unroll
            for (int mt = 0; mt < 2; ++mt)
                af[mt] = *(const bf16x8*)&A_s[wm * 32 + mt * 16 + (lane & 15)][k0];
            #pragma unroll
            for (int nt = 0; nt < 4; ++nt)
                bfr[nt] = *(const bf16x8*)&B_s[wn * 64 + nt * 16 + (lane & 15)][k0];
            #pragma unroll
            for (int mt = 0; mt < 2; ++mt)
                #pragma unroll
                for (int nt = 0; nt < 4; ++nt)
                    acc[mt][nt] = __builtin_amdgcn_mfma_f32_16x16x32_bf16(
                        af[mt], bfr[nt], acc[mt][nt], 0, 0, 0);
        }
        if (ch + 1 < NCH) __syncthreads();
    }

    int fbase = wn * 64;
    #pragma unroll
    for (int mt = 0; mt < 2; ++mt) {
        #pragma unroll
        for (int rg = 0; rg < 4; ++rg) {
            int nl = wm * 32 + mt * 16 + ((lane >> 4) << 2) + rg;
            int node = n0 + nl;
            if (node >= NN) continue;
            #pragma unroll
            for (int nt = 0; nt < 4; ++nt) {
                int f = fbase + nt * 16 + (lane & 15);
                float v = acc[mt][nt][rg];
                if (EPI == 0) {
                    hs[(size_t)node * HSW + f] = f2b(v + bias1[f]);
                } else if (EPI == 1) {
                    int d = deg_s[nl];
                    float o = v * (1.f / (float)max(d, 1)) + ((d > 0) ? bias1[f] : 0.f);
                    hs[(size_t)node * HSW + 128 + f] = f2b(o);
                } else {
                    float o = fmaxf(v + bias1[f] + bias2[f], 0.f);
                    if (EPI == 2) hs[(size_t)node * HSW + f] = f2b(o);
                    else          outf[(size_t)node * DH + f] = o;
                }
            }
        }
    }
}

// ---------------- launch ----------------
extern "C" void kernel_launch(void* const* d_in, const int* in_sizes, int n_in,
                              void* d_out, int out_size, void* d_ws, size_t ws_size,
                              hipStream_t stream) {
    const float* x      = (const float*)d_in[0];
    const float* in_W   = (const float*)d_in[1];
    const float* in_b   = (const float*)d_in[2];
    const float* rel_e  = (const float*)d_in[3];
    const float* msg_W  = (const float*)d_in[4];
    const float* msg_b  = (const float*)d_in[5];
    const float* self_b = (const float*)d_in[7];
    const float* self_W = (const float*)d_in[6];
    const float* neigh_W= (const float*)d_in[8];
    const float* neigh_b= (const float*)d_in[9];
    const int* e_src    = (const int*)d_in[10];
    const int* e_dst    = (const int*)d_in[11];
    const int* r_ids    = (const int*)d_in[12];

    char* ws = (char*)d_ws;
    size_t off = 0;
    ushort* HS   = (ushort*)(ws + off); off += (size_t)NN * HSW * 2;      // 27.2 MB
    ushort* inWb = (ushort*)(ws + off); off += (size_t)DH * DH * 2;
    ushort* B1   = (ushort*)(ws + off); off += 2 * (size_t)DH * 144 * 2;
    ushort* Wc2b = (ushort*)(ws + off); off += 2 * (size_t)DH * 256 * 2;
    int* deg  = (int*)(ws + off);
    int* cnt  = deg + NN;
    int* rp   = cnt + (size_t)NN * RR;
    int* fill = rp + NN + 1;
    int* bsum = fill + NN;
    int* boff = bsum + 256;
    int* col  = boff + 256;                                               // total ~34.5 MB

    hipMemsetAsync(deg, 0, sizeof(int) * (NN + (size_t)NN * RR), stream);

    k_count<<<(EE + 255) / 256, 256, 0, stream>>>(e_dst, r_ids, deg, cnt);
    k_scan_part<<<SCAN_B, 256, 0, stream>>>(deg, rp, bsum);
    k_scan_bsum<<<1, 256, 0, stream>>>(bsum, boff);
    k_scan_add<<<SCAN_B, 256, 0, stream>>>(boff, rp, fill);
    k_fill<<<(EE + 255) / 256, 256, 0, stream>>>(e_src, e_dst, fill, col);

    k_cntbf<<<(NN * RR + 255) / 256, 256, 0, stream>>>(cnt, HS);
    k_prep_inWb<<<64, 256, 0, stream>>>(in_W, inWb);
    k_prep_msgWb<<<1, 256, 0, stream>>>(msg_W, rel_e, B1);
    k_prep_wc2b<<<256, 256, 0, stream>>>(self_W, neigh_W, Wc2b);

    const int GB = (NN + 63) / 64;   // 782
    // h = x @ in_W.T + in_b   -> HS[:,0:128] bf16
    k_mm<128, 0, 0><<<GB, 256, 0, stream>>>(x, inWb, in_b, nullptr, nullptr, HS, nullptr);

    for (int l = 0; l < 2; ++l) {
        k_seg<<<(NN + 3) / 4, 256, 0, stream>>>(HS, rp, col);
        // agg: A = HS[:,128:272] (K=144 = segsum|cnt), B = [msg_Wh | RM]
        k_mm<144, 1, 1><<<GB, 256, 0, stream>>>(HS + 128, B1 + (size_t)l * DH * 144,
                                                msg_b + l * DH, nullptr, deg, HS, nullptr);
        if (l == 0)
            k_mm<256, 2, 2><<<GB, 256, 0, stream>>>(HS, Wc2b, self_b, neigh_b,
                                                    nullptr, HS, nullptr);
        else
            k_mm<256, 3, 2><<<GB, 256, 0, stream>>>(HS, Wc2b + (size_t)DH * 256,
                                                    self_b + DH, neigh_b + DH,
                                                    nullptr, HS, (float*)d_out);
    }
}

// Round 7
// 395.259 us; speedup vs baseline: 2.5439x; 1.1046x over previous
//
#include <hip/hip_runtime.h>
#include <hip/hip_bf16.h>

#define NN 50000
#define EE 800000
#define DH 128
#define RDIM 32
#define RR 16
#define HRD 160
#define HSW 384            // HS row (ushort): [128 h | 128 S/agg | 128 RMacc]
#define SCAN_B ((NN + 255) / 256)

typedef __attribute__((ext_vector_type(8))) short bf16x8;
typedef __attribute__((ext_vector_type(4))) float f32x4;

__device__ __forceinline__ ushort f2b(float v) {      // f32 -> bf16 RNE
    uint u = __float_as_uint(v);
    return (ushort)((u + 0x7fffu + ((u >> 16) & 1u)) >> 16);
}
__device__ __forceinline__ float b2f(ushort b) { return __uint_as_float(((uint)b) << 16); }

// ---------------- CSR build ----------------
// k_count: deg atomic returns per-edge ordinal (slot within its dst segment).
__global__ __launch_bounds__(256) void k_count(const int* __restrict__ dst,
                                               int* deg, int* ord) {
    int e = blockIdx.x * 256 + threadIdx.x;
    if (e < EE) ord[e] = atomicAdd(&deg[dst[e]], 1);
}

__global__ __launch_bounds__(256) void k_scan_part(const int* __restrict__ deg,
                                                   int* rp, int* bsum) {
    __shared__ int s[256];
    int tid = threadIdx.x;
    int i = blockIdx.x * 256 + tid;
    int v = (i < NN) ? deg[i] : 0;
    s[tid] = v;
    __syncthreads();
    for (int off = 1; off < 256; off <<= 1) {
        int t = (tid >= off) ? s[tid - off] : 0;
        __syncthreads();
        s[tid] += t;
        __syncthreads();
    }
    if (i < NN) rp[i] = s[tid] - v;
    if (tid == 255) bsum[blockIdx.x] = s[255];
}

__global__ __launch_bounds__(256) void k_scan_bsum(const int* __restrict__ bsum, int* boff) {
    __shared__ int s[256];
    int tid = threadIdx.x;
    int v = (tid < SCAN_B) ? bsum[tid] : 0;
    s[tid] = v;
    __syncthreads();
    for (int off = 1; off < 256; off <<= 1) {
        int t = (tid >= off) ? s[tid - off] : 0;
        __syncthreads();
        s[tid] += t;
        __syncthreads();
    }
    boff[tid] = s[tid] - v;
}

__global__ __launch_bounds__(256) void k_scan_add(const int* __restrict__ boff, int* rp) {
    int i = blockIdx.x * 256 + threadIdx.x;
    if (i < NN) rp[i] += boff[blockIdx.x];
    if (i == 0) rp[NN] = EE;
}

// col[p] = src | rel<<16  (src < 65536, rel < 16)  — no atomic (ordinal precomputed)
__global__ __launch_bounds__(256) void k_fill(const int* __restrict__ src,
                                              const int* __restrict__ dst,
                                              const int* __restrict__ rel,
                                              const int* __restrict__ ord,
                                              const int* __restrict__ rp,
                                              int* __restrict__ col) {
    int e = blockIdx.x * 256 + threadIdx.x;
    if (e < EE) {
        int p = rp[dst[e]] + ord[e];
        col[p] = src[e] | (rel[e] << 16);
    }
}

// ---------------- weight prep ----------------

__global__ __launch_bounds__(256) void k_prep_inWb(const float* __restrict__ w,
                                                   ushort* __restrict__ o) {
    int i = blockIdx.x * 256 + threadIdx.x;          // 16384
    o[i] = f2b(w[i]);
}

// B1[l][f][0..127] = msg_Wh[l][f][:] bf16;  RMf32[l][r][f] = (rel_emb[l] @ msg_Wr[l].T)[r][f]
__global__ __launch_bounds__(256) void k_prep_msgWb(const float* __restrict__ msgW,
                                                    const float* __restrict__ relE,
                                                    ushort* __restrict__ B1,
                                                    float* __restrict__ RMf32) {
    int t = threadIdx.x;                              // 1 block x 256
    int l = t >> 7, f = t & 127;
    const float* mw = msgW + (size_t)l * DH * HRD + f * HRD;
    ushort* out = B1 + ((size_t)l * DH + f) * DH;
    for (int k = 0; k < DH; ++k) out[k] = f2b(mw[k]);
    for (int r = 0; r < RR; ++r) {
        float acc = 0.f;
        for (int c = 0; c < RDIM; ++c)
            acc += relE[l * RR * RDIM + r * RDIM + c] * mw[DH + c];
        RMf32[(size_t)l * RR * DH + r * DH + f] = acc;
    }
}

// Wc2b[l][f][0..127]=self_W, [128..255]=neigh_W  (bf16)
__global__ __launch_bounds__(256) void k_prep_wc2b(const float* __restrict__ selfW,
                                                   const float* __restrict__ neighW,
                                                   ushort* __restrict__ o) {
    int idx = blockIdx.x * 256 + threadIdx.x;        // 65536
    int l = idx >> 15, rem = idx & 32767;
    int f = rem >> 8, k = rem & 255;
    float v = (k < DH) ? selfW[(size_t)l * DH * DH + f * DH + k]
                       : neighW[(size_t)l * DH * DH + f * DH + (k - DH)];
    o[idx] = f2b(v);
}

// ---------------- gather ----------------
// HS[n][128..255] = sum_{e:dst=n} HS[src_e][0..127];  HS[n][256..383] = sum_e RM[rel_e][:]
__global__ __launch_bounds__(256) void k_seg(ushort* __restrict__ hs,
                                             const int* __restrict__ rp,
                                             const int* __restrict__ col,
                                             const float* __restrict__ RM) {
    __shared__ float RM_s[RR * DH];                   // 8 KB
    int t = threadIdx.x;
    for (int i = t; i < RR * DH; i += 256) RM_s[i] = RM[i];
    __syncthreads();
    int wid = t >> 6, lane = t & 63;
    int n = blockIdx.x * 4 + wid;
    if (n >= NN) return;
    int beg = rp[n], end = rp[n + 1];
    float ax = 0.f, ay = 0.f, rx = 0.f, ry = 0.f;
    const float* rm0 = RM_s + lane * 2;
    for (int j0 = beg; j0 < end; j0 += 64) {
        int myc = (j0 + lane < end) ? col[j0 + lane] : 0;
        int m = min(64, end - j0);
        for (int jj = 0; jj < m; ++jj) {
            int packed = __shfl(myc, jj, 64);
            int sidx = packed & 0xffff;
            int rel = packed >> 16;
            uint v = *(const uint*)(hs + (size_t)sidx * HSW + lane * 2);
            ax += b2f((ushort)(v & 0xffffu));
            ay += b2f((ushort)(v >> 16));
            rx += rm0[rel * DH];
            ry += rm0[rel * DH + 1];
        }
    }
    uint ps = ((uint)f2b(ay) << 16) | (uint)f2b(ax);
    uint pr = ((uint)f2b(ry) << 16) | (uint)f2b(rx);
    *(uint*)(hs + (size_t)n * HSW + 128 + lane * 2) = ps;
    *(uint*)(hs + (size_t)n * HSW + 256 + lane * 2) = pr;
}

// ---------------- MFMA GEMM: out[n][f] = epi( sum_k A[n][k]*B[f][k] ) ----------------
// 256 thr = 4 waves (2M x 2N). Block tile 64 nodes x 128 f. K chunked at 128.
// AMODE 0: A = x (f32, convert on stage)   1: A = bf16, row stride HSW ushorts.
// EPI 0: +b1 -> bf16 HS[:,0:128]                          (inproj)
// EPI 1: (v+RMacc)/max(d,1) + (d>0)*b1 -> bf16 HS[:,128:256]   (agg)
// EPI 2: relu(v+b1+b2) -> bf16 HS[:,0:128]   EPI 3: same -> f32 d_out
template <int K, int EPI, int AMODE>
__global__ __launch_bounds__(256) void k_mm(const void* __restrict__ Araw,
                                            const ushort* __restrict__ B,
                                            const float* __restrict__ bias1,
                                            const float* __restrict__ bias2,
                                            const int* __restrict__ deg,
                                            ushort* __restrict__ hs,
                                            float* __restrict__ outf) {
    constexpr int KC = (K == 256) ? 128 : K;
    constexpr int NCH = K / KC;
    constexpr int KP = KC + 8;
    __shared__ ushort A_s[64][KP];
    __shared__ ushort B_s[128][KP];
    __shared__ int deg_s[64];
    int t = threadIdx.x;
    int n0 = blockIdx.x * 64;
    int lane = t & 63, wid = t >> 6;
    int wm = wid >> 1, wn = wid & 1;

    if (EPI == 1 && t < 64) {
        int node = n0 + t;
        deg_s[t] = (node < NN) ? deg[node] : 1;
    }

    f32x4 acc[2][4];
    #pragma unroll
    for (int mt = 0; mt < 2; ++mt)
        #pragma unroll
        for (int nt = 0; nt < 4; ++nt) acc[mt][nt] = (f32x4)0.0f;

    for (int ch = 0; ch < NCH; ++ch) {
        int kc0 = ch * KC;
        if (AMODE == 0) {
            const float4* x4 = (const float4*)Araw;            // [NN][128] f32
            for (int idx = t; idx < 64 * (KC / 4); idx += 256) {
                int r = idx / (KC / 4), c = idx % (KC / 4);
                int node = min(n0 + r, NN - 1);
                float4 v = x4[(size_t)node * 32 + c];
                ushort* dstp = &A_s[r][c * 4];
                dstp[0] = f2b(v.x); dstp[1] = f2b(v.y);
                dstp[2] = f2b(v.z); dstp[3] = f2b(v.w);
            }
        } else {
            const ushort* Ab = (const ushort*)Araw;
            for (int idx = t; idx < 64 * (KC / 8); idx += 256) {
                int r = idx / (KC / 8), c = idx % (KC / 8);
                int node = min(n0 + r, NN - 1);
                *(uint4*)&A_s[r][c * 8] =
                    *(const uint4*)(Ab + (size_t)node * HSW + kc0 + c * 8);
            }
        }
        for (int idx = t; idx < 128 * (KC / 8); idx += 256) {
            int r = idx / (KC / 8), c = idx % (KC / 8);
            *(uint4*)&B_s[r][c * 8] =
                *(const uint4*)(B + (size_t)r * K + kc0 + c * 8);
        }
        __syncthreads();

        #pragma unroll
        for (int ks = 0; ks < KC / 32; ++ks) {
            int k0 = ks * 32 + (lane >> 4) * 8;
            bf16x8 af[2], bfr[4];
            #pragma unroll
            for (int mt = 0; mt < 2; ++mt)
                af[mt] = *(const bf16x8*)&A_s[wm * 32 + mt * 16 + (lane & 15)][k0];
            #pragma unroll
            for (int nt = 0; nt < 4; ++nt)
                bfr[nt] = *(const bf16x8*)&B_s[wn * 64 + nt * 16 + (lane & 15)][k0];
            #pragma unroll
            for (int mt = 0; mt < 2; ++mt)
                #pragma unroll
                for (int nt = 0; nt < 4; ++nt)
                    acc[mt][nt] = __builtin_amdgcn_mfma_f32_16x16x32_bf16(
                        af[mt], bfr[nt], acc[mt][nt], 0, 0, 0);
        }
        if (ch + 1 < NCH) __syncthreads();
    }

    int fbase = wn * 64;
    #pragma unroll
    for (int mt = 0; mt < 2; ++mt) {
        #pragma unroll
        for (int rg = 0; rg < 4; ++rg) {
            int nl = wm * 32 + mt * 16 + ((lane >> 4) << 2) + rg;
            int node = n0 + nl;
            if (node >= NN) continue;
            #pragma unroll
            for (int nt = 0; nt < 4; ++nt) {
                int f = fbase + nt * 16 + (lane & 15);
                float v = acc[mt][nt][rg];
                if (EPI == 0) {
                    hs[(size_t)node * HSW + f] = f2b(v + bias1[f]);
                } else if (EPI == 1) {
                    int d = deg_s[nl];
                    float rmacc = b2f(hs[(size_t)node * HSW + 256 + f]);
                    float o = (v + rmacc) * (1.f / (float)max(d, 1))
                              + ((d > 0) ? bias1[f] : 0.f);
                    hs[(size_t)node * HSW + 128 + f] = f2b(o);
                } else {
                    float o = fmaxf(v + bias1[f] + bias2[f], 0.f);
                    if (EPI == 2) hs[(size_t)node * HSW + f] = f2b(o);
                    else          outf[(size_t)node * DH + f] = o;
                }
            }
        }
    }
}

// ---------------- launch ----------------
extern "C" void kernel_launch(void* const* d_in, const int* in_sizes, int n_in,
                              void* d_out, int out_size, void* d_ws, size_t ws_size,
                              hipStream_t stream) {
    const float* x      = (const float*)d_in[0];
    const float* in_W   = (const float*)d_in[1];
    const float* in_b   = (const float*)d_in[2];
    const float* rel_e  = (const float*)d_in[3];
    const float* msg_W  = (const float*)d_in[4];
    const float* msg_b  = (const float*)d_in[5];
    const float* self_W = (const float*)d_in[6];
    const float* self_b = (const float*)d_in[7];
    const float* neigh_W= (const float*)d_in[8];
    const float* neigh_b= (const float*)d_in[9];
    const int* e_src    = (const int*)d_in[10];
    const int* e_dst    = (const int*)d_in[11];
    const int* r_ids    = (const int*)d_in[12];

    char* ws = (char*)d_ws;
    size_t off = 0;
    ushort* HS   = (ushort*)(ws + off); off += (size_t)NN * HSW * 2;      // 38.4 MB
    ushort* inWb = (ushort*)(ws + off); off += (size_t)DH * DH * 2;
    ushort* B1   = (ushort*)(ws + off); off += 2 * (size_t)DH * DH * 2;
    ushort* Wc2b = (ushort*)(ws + off); off += 2 * (size_t)DH * 256 * 2;
    float*  RMf  = (float*)(ws + off);  off += 2 * (size_t)RR * DH * 4;
    int* deg  = (int*)(ws + off);
    int* rp   = deg + NN;
    int* bsum = rp + NN + 1;
    int* boff = bsum + 256;
    int* ord  = boff + 256;
    int* col  = ord + EE;                                                 // total ~45 MB

    hipMemsetAsync(deg, 0, sizeof(int) * NN, stream);

    k_count<<<(EE + 255) / 256, 256, 0, stream>>>(e_dst, deg, ord);
    k_scan_part<<<SCAN_B, 256, 0, stream>>>(deg, rp, bsum);
    k_scan_bsum<<<1, 256, 0, stream>>>(bsum, boff);
    k_scan_add<<<SCAN_B, 256, 0, stream>>>(boff, rp);
    k_fill<<<(EE + 255) / 256, 256, 0, stream>>>(e_src, e_dst, r_ids, ord, rp, col);

    k_prep_inWb<<<64, 256, 0, stream>>>(in_W, inWb);
    k_prep_msgWb<<<1, 256, 0, stream>>>(msg_W, rel_e, B1, RMf);
    k_prep_wc2b<<<256, 256, 0, stream>>>(self_W, neigh_W, Wc2b);

    const int GB = (NN + 63) / 64;   // 782
    // h = x @ in_W.T + in_b   -> HS[:,0:128] bf16
    k_mm<128, 0, 0><<<GB, 256, 0, stream>>>(x, inWb, in_b, nullptr, nullptr, HS, nullptr);

    for (int l = 0; l < 2; ++l) {
        k_seg<<<(NN + 3) / 4, 256, 0, stream>>>(HS, rp, col, RMf + (size_t)l * RR * DH);
        // agg = (S@msg_Wh.T + RMacc)/max(deg,1) + (deg>0)*msg_b  -> HS[:,128:256]
        k_mm<128, 1, 1><<<GB, 256, 0, stream>>>(HS + 128, B1 + (size_t)l * DH * DH,
                                                msg_b + l * DH, nullptr, deg, HS, nullptr);
        if (l == 0)
            k_mm<256, 2, 1><<<GB, 256, 0, stream>>>(HS, Wc2b, self_b, neigh_b,
                                                    nullptr, HS, nullptr);
        else
            k_mm<256, 3, 1><<<GB, 256, 0, stream>>>(HS, Wc2b + (size_t)DH * 256,
                                                    self_b + DH, neigh_b + DH,
                                                    nullptr, HS, (float*)d_out);
    }
}